// Round 1
// baseline (158.684 us; speedup 1.0000x reference)
//
#include <hip/hip_runtime.h>
#include <hip/hip_bf16.h>

#define N_NODES 30000
#define T_TYPES 4
#define F_DIM   128
#define H_HEADS 8

typedef __bf16 bf16x8 __attribute__((ext_vector_type(8)));
typedef __bf16 bf16x4 __attribute__((ext_vector_type(4)));
typedef float  floatx4 __attribute__((ext_vector_type(4)));

// ws layout:
//   [0,      64)      counts[4] (zeroed by prep each launch)
//   [64,     480064)  reorder[4*N] int  (type t region at t*N)
//   [480256, 611328)  node_proj bf16  (4*128*128)
//   [611328, 1135616) edge_proj bf16  (16*128*128)
#define WS_REORDER 64
#define WS_NPB     480256
#define WS_EPB     611328

// ---------------- kernel 0: convert proj tables to bf16, zero counts ----------
__global__ __launch_bounds__(256) void prep_kernel(
    const float* __restrict__ node_proj, const float* __restrict__ edge_proj,
    __bf16* __restrict__ npb, __bf16* __restrict__ epb, int* __restrict__ counts)
{
    int i = blockIdx.x * 256 + threadIdx.x;       // 0..81919, each converts 4 floats
    if (i < 4) counts[i] = 0;
    int base = i * 4;
    float4 v;
    __bf16* dst;
    if (base < T_TYPES * F_DIM * F_DIM) {
        v = ((const float4*)node_proj)[i];
        dst = npb + base;
    } else {
        int off = base - T_TYPES * F_DIM * F_DIM;
        v = ((const float4*)edge_proj)[off >> 2];
        dst = epb + off;
    }
    bf16x4 w = { (__bf16)v.x, (__bf16)v.y, (__bf16)v.z, (__bf16)v.w };
    *(bf16x4*)dst = w;
}

// ---------------- kernel 1: bucket nodes by type (wave-aggregated atomics) ----
__global__ __launch_bounds__(256) void bucket_kernel(
    const int* __restrict__ mask, int* __restrict__ counts, int* __restrict__ reorder)
{
    int n = blockIdx.x * 256 + threadIdx.x;
    int lane = threadIdx.x & 63;
    int t = (n < N_NODES) ? mask[n] : -1;
    #pragma unroll
    for (int tt = 0; tt < T_TYPES; ++tt) {
        unsigned long long b = __ballot(t == tt);
        if (b == 0ull) continue;                 // wave-uniform
        int cnt = __popcll(b);
        int leader = __ffsll((unsigned long long)b) - 1;
        int base = 0;
        if (lane == leader) base = atomicAdd(&counts[tt], cnt);
        base = __shfl(base, leader);
        if (t == tt) {
            int prefix = __popcll(b & ((1ull << lane) - 1ull));
            reorder[tt * N_NODES + base + prefix] = n;
        }
    }
}

// ---------------- kernel 2: fused proj-GEMM + scores + head-softmax ----------
// Block: 256 threads (4 waves), 32 nodes of one type, all 128 outputs.
// Wave w owns g-slice [32w, 32w+32) = heads {2w, 2w+1}.
__global__ __launch_bounds__(256) void main_kernel(
    const float* __restrict__ feature, const float* __restrict__ edge_fea,
    const int* __restrict__ counts, const int* __restrict__ reorder,
    const __bf16* __restrict__ npb, const __bf16* __restrict__ epb,
    float* __restrict__ out)
{
    const int t = blockIdx.y;
    const int Nt = counts[t];
    const int start = blockIdx.x * 32;
    if (start >= Nt) return;
    const int valid = min(32, Nt - start);

    // +8 bf16 row pad (16B): rows land 4 banks apart -> only 2-way aliasing (free)
    __shared__ __bf16 Afeat[32][136];
    __shared__ __bf16 Aedge[4][32][136];
    __shared__ float  sc[32][4][H_HEADS];
    __shared__ int    nidx[32];

    const int tid = threadIdx.x;
    if (tid < 32) {
        int s = (tid < valid) ? tid : (valid - 1);   // clamp-dup tail nodes
        nidx[tid] = reorder[t * N_NODES + start + s];
    }
    __syncthreads();

    // ---- stage A: fp32 global -> bf16 LDS (coalesced float4 per row) ----
    const int colv = tid & 31;     // float4 index within a 128-float row
    const int rowg = tid >> 5;     // 8 rows in flight
    #pragma unroll
    for (int it = 0; it < 4; ++it) {             // 32 feature rows
        int row = it * 8 + rowg;
        const float* src = feature + (long)nidx[row] * F_DIM;
        float4 v = ((const float4*)src)[colv];
        bf16x4 w = { (__bf16)v.x, (__bf16)v.y, (__bf16)v.z, (__bf16)v.w };
        *(bf16x4*)(&Afeat[row][0] + colv * 4) = w;
    }
    #pragma unroll
    for (int it = 0; it < 16; ++it) {            // 128 edge rows
        int row = it * 8 + rowg;                 // 0..127
        int j = row >> 5, r = row & 31;
        const float* src = edge_fea + ((long)nidx[r] * 4 + j) * F_DIM;
        float4 v = ((const float4*)src)[colv];
        bf16x4 w = { (__bf16)v.x, (__bf16)v.y, (__bf16)v.z, (__bf16)v.w };
        *(bf16x4*)(&Aedge[j][r][0] + colv * 4) = w;
    }
    __syncthreads();

    const int lane = tid & 63;
    const int wave = tid >> 6;
    const int ml   = lane & 15;
    const int quad = lane >> 4;
    const int g0   = wave * 32;

    // ---- node GEMM: accN[mt][nt] = feature_tile @ node_proj[t]^T ----
    floatx4 accN[2][2] = {};
    {
        const __bf16* a0 = &Afeat[ml][quad * 8];
        const __bf16* a1 = &Afeat[16 + ml][quad * 8];
        const __bf16* b0 = npb + t * (F_DIM * F_DIM) + (g0 + ml) * F_DIM + quad * 8;
        const __bf16* b1 = b0 + 16 * F_DIM;
        #pragma unroll
        for (int k0 = 0; k0 < 128; k0 += 32) {
            bf16x8 A0 = *(const bf16x8*)(a0 + k0);
            bf16x8 A1 = *(const bf16x8*)(a1 + k0);
            bf16x8 B0 = *(const bf16x8*)(b0 + k0);
            bf16x8 B1 = *(const bf16x8*)(b1 + k0);
            accN[0][0] = __builtin_amdgcn_mfma_f32_16x16x32_bf16(A0, B0, accN[0][0], 0, 0, 0);
            accN[0][1] = __builtin_amdgcn_mfma_f32_16x16x32_bf16(A0, B1, accN[0][1], 0, 0, 0);
            accN[1][0] = __builtin_amdgcn_mfma_f32_16x16x32_bf16(A1, B0, accN[1][0], 0, 0, 0);
            accN[1][1] = __builtin_amdgcn_mfma_f32_16x16x32_bf16(A1, B1, accN[1][1], 0, 0, 0);
        }
    }

    // ---- edge GEMMs + fused score reduction ----
    #pragma unroll
    for (int j = 0; j < 4; ++j) {
        floatx4 accE[2][2] = {};
        const __bf16* a0 = &Aedge[j][ml][quad * 8];
        const __bf16* a1 = &Aedge[j][16 + ml][quad * 8];
        const __bf16* b0 = epb + (t * 4 + j) * (F_DIM * F_DIM) + (g0 + ml) * F_DIM + quad * 8;
        const __bf16* b1 = b0 + 16 * F_DIM;
        #pragma unroll
        for (int k0 = 0; k0 < 128; k0 += 32) {
            bf16x8 A0 = *(const bf16x8*)(a0 + k0);
            bf16x8 A1 = *(const bf16x8*)(a1 + k0);
            bf16x8 B0 = *(const bf16x8*)(b0 + k0);
            bf16x8 B1 = *(const bf16x8*)(b1 + k0);
            accE[0][0] = __builtin_amdgcn_mfma_f32_16x16x32_bf16(A0, B0, accE[0][0], 0, 0, 0);
            accE[0][1] = __builtin_amdgcn_mfma_f32_16x16x32_bf16(A0, B1, accE[0][1], 0, 0, 0);
            accE[1][0] = __builtin_amdgcn_mfma_f32_16x16x32_bf16(A1, B0, accE[1][0], 0, 0, 0);
            accE[1][1] = __builtin_amdgcn_mfma_f32_16x16x32_bf16(A1, B1, accE[1][1], 0, 0, 0);
        }
        // score[m][h=2w+nt][j] = (1/4) * sum_d node_p * edge_p ; d == lane&15
        #pragma unroll
        for (int mt = 0; mt < 2; ++mt) {
            #pragma unroll
            for (int nt = 0; nt < 2; ++nt) {
                floatx4 p = accN[mt][nt] * accE[mt][nt];
                #pragma unroll
                for (int s = 1; s < 16; s <<= 1) {   // butterfly within 16-lane group
                    p.x += __shfl_xor(p.x, s);
                    p.y += __shfl_xor(p.y, s);
                    p.z += __shfl_xor(p.z, s);
                    p.w += __shfl_xor(p.w, s);
                }
                if (ml == 0) {
                    int h = wave * 2 + nt;
                    int mb = mt * 16 + quad * 4;      // C/D row = quad*4+reg
                    sc[mb + 0][j][h] = p.x * 0.25f;
                    sc[mb + 1][j][h] = p.y * 0.25f;
                    sc[mb + 2][j][h] = p.z * 0.25f;
                    sc[mb + 3][j][h] = p.w * 0.25f;
                }
            }
        }
    }
    __syncthreads();

    // ---- softmax over heads (axis=1 of [N,H,1,T]) -> out[n][j][h] ----
    if (tid < 128) {
        int node = tid >> 2, j = tid & 3;
        if (node < valid) {
            float v[8], m = -1e30f;
            #pragma unroll
            for (int h = 0; h < 8; ++h) { v[h] = sc[node][j][h]; m = fmaxf(m, v[h]); }
            float s = 0.f;
            #pragma unroll
            for (int h = 0; h < 8; ++h) { v[h] = __expf(v[h] - m); s += v[h]; }
            float r = 1.0f / s;
            float* o = out + (long)nidx[node] * (T_TYPES * H_HEADS) + j * H_HEADS;
            float4 o0 = { v[0] * r, v[1] * r, v[2] * r, v[3] * r };
            float4 o1 = { v[4] * r, v[5] * r, v[6] * r, v[7] * r };
            ((float4*)o)[0] = o0;
            ((float4*)o)[1] = o1;
        }
    }
}

extern "C" void kernel_launch(void* const* d_in, const int* in_sizes, int n_in,
                              void* d_out, int out_size, void* d_ws, size_t ws_size,
                              hipStream_t stream) {
    const float* feature   = (const float*)d_in[0];
    const float* edge_fea  = (const float*)d_in[1];
    const int*   mask      = (const int*)d_in[2];
    const float* node_proj = (const float*)d_in[3];
    const float* edge_proj = (const float*)d_in[4];
    float* out = (float*)d_out;

    char* ws = (char*)d_ws;
    int*    counts  = (int*)ws;
    int*    reorder = (int*)(ws + WS_REORDER);
    __bf16* npb     = (__bf16*)(ws + WS_NPB);
    __bf16* epb     = (__bf16*)(ws + WS_EPB);

    prep_kernel<<<320, 256, 0, stream>>>(node_proj, edge_proj, npb, epb, counts);
    bucket_kernel<<<(N_NODES + 255) / 256, 256, 0, stream>>>(mask, counts, reorder);
    dim3 grid((N_NODES + 31) / 32, T_TYPES);
    main_kernel<<<grid, 256, 0, stream>>>(feature, edge_fea, counts, reorder, npb, epb, out);
}

// Round 2
// 144.950 us; speedup vs baseline: 1.0948x; 1.0948x over previous
//
#include <hip/hip_runtime.h>
#include <hip/hip_bf16.h>

#define N_NODES 30000
#define T_TYPES 4
#define F_DIM   128
#define H_HEADS 8

typedef __bf16 bf16x8 __attribute__((ext_vector_type(8)));
typedef __bf16 bf16x4 __attribute__((ext_vector_type(4)));
typedef float  floatx4 __attribute__((ext_vector_type(4)));

// ws layout:
//   [0,      64)      counts[4] (zeroed by prep each launch)
//   [64,     480064)  reorder[4*N] int  (type t region at t*N)
//   [480256, 611328)  node_proj bf16  (4*128*128)
//   [611328, 1135616) edge_proj bf16  (16*128*128)
#define WS_REORDER 64
#define WS_NPB     480256
#define WS_EPB     611328

// 16-lane (row) sum via DPP on the VALU pipe — no LDS traffic.
// stages: xor1 (quad_perm {1,0,3,2}=0xB1), xor2 (quad_perm {2,3,0,1}=0x4E),
//         row_half_mirror (0x141), row_mirror (0x140)
template <int CTRL>
static __device__ __forceinline__ float dpp_add(float x) {
    int xi = __builtin_bit_cast(int, x);
    int yi = __builtin_amdgcn_update_dpp(xi, xi, CTRL, 0xF, 0xF, true);
    return x + __builtin_bit_cast(float, yi);
}
static __device__ __forceinline__ float sum16(float x) {
    x = dpp_add<0xB1>(x);
    x = dpp_add<0x4E>(x);
    x = dpp_add<0x141>(x);
    x = dpp_add<0x140>(x);
    return x;
}

// ---------------- kernel 0: convert proj tables to bf16, zero counts ----------
__global__ __launch_bounds__(256) void prep_kernel(
    const float* __restrict__ node_proj, const float* __restrict__ edge_proj,
    __bf16* __restrict__ npb, __bf16* __restrict__ epb, int* __restrict__ counts)
{
    int i = blockIdx.x * 256 + threadIdx.x;       // 0..81919, each converts 4 floats
    if (i < 4) counts[i] = 0;
    int base = i * 4;
    float4 v;
    __bf16* dst;
    if (base < T_TYPES * F_DIM * F_DIM) {
        v = ((const float4*)node_proj)[i];
        dst = npb + base;
    } else {
        int off = base - T_TYPES * F_DIM * F_DIM;
        v = ((const float4*)edge_proj)[off >> 2];
        dst = epb + off;
    }
    bf16x4 w = { (__bf16)v.x, (__bf16)v.y, (__bf16)v.z, (__bf16)v.w };
    *(bf16x4*)dst = w;
}

// ---------------- kernel 1: bucket nodes by type (wave-aggregated atomics) ----
__global__ __launch_bounds__(256) void bucket_kernel(
    const int* __restrict__ mask, int* __restrict__ counts, int* __restrict__ reorder)
{
    int n = blockIdx.x * 256 + threadIdx.x;
    int lane = threadIdx.x & 63;
    int t = (n < N_NODES) ? mask[n] : -1;
    #pragma unroll
    for (int tt = 0; tt < T_TYPES; ++tt) {
        unsigned long long b = __ballot(t == tt);
        if (b == 0ull) continue;                 // wave-uniform
        int cnt = __popcll(b);
        int leader = __ffsll((unsigned long long)b) - 1;
        int base = 0;
        if (lane == leader) base = atomicAdd(&counts[tt], cnt);
        base = __shfl(base, leader);
        if (t == tt) {
            int prefix = __popcll(b & ((1ull << lane) - 1ull));
            reorder[tt * N_NODES + base + prefix] = n;
        }
    }
}

// ---------------- kernel 2: fused proj-GEMM + scores + head-softmax ----------
// Block: 512 threads (8 waves), 32 nodes of one type, all 128 outputs.
// Wave w owns g-slice [16w, 16w+16) == head h=w exactly (d = lane&15).
__global__ __launch_bounds__(512) void main_kernel(
    const float* __restrict__ feature, const float* __restrict__ edge_fea,
    const int* __restrict__ counts, const int* __restrict__ reorder,
    const __bf16* __restrict__ npb, const __bf16* __restrict__ epb,
    float* __restrict__ out)
{
    const int b = blockIdx.x;
    const int t = b & 3;                       // interleave types across blocks
    const int start = (b >> 2) * 32;
    const int Nt = counts[t];
    if (start >= Nt) return;
    const int valid = min(32, Nt - start);

    // +8 bf16 row pad (16B): rows land 4 banks apart -> only 2-way aliasing (free)
    __shared__ __bf16 Afeat[32][136];
    __shared__ __bf16 Aedge[4][32][136];
    __shared__ float  sc[32][4][H_HEADS];
    __shared__ int    nidx[32];

    const int tid = threadIdx.x;
    if (tid < 32) {
        int s = (tid < valid) ? tid : (valid - 1);   // clamp-dup tail nodes
        nidx[tid] = reorder[t * N_NODES + start + s];
    }
    __syncthreads();

    // ---- stage A: fp32 global -> bf16 LDS (coalesced float4 per row) ----
    const int colv = tid & 31;     // float4 index within a 128-float row
    const int rowg = tid >> 5;     // 16 rows in flight
    #pragma unroll
    for (int it = 0; it < 2; ++it) {             // 32 feature rows
        int row = it * 16 + rowg;
        float4 v = ((const float4*)(feature + (long)nidx[row] * F_DIM))[colv];
        bf16x4 w = { (__bf16)v.x, (__bf16)v.y, (__bf16)v.z, (__bf16)v.w };
        *(bf16x4*)(&Afeat[row][0] + colv * 4) = w;
    }
    #pragma unroll
    for (int it = 0; it < 8; ++it) {             // 128 edge rows
        int row = it * 16 + rowg;                // 0..127
        int j = row >> 5, r = row & 31;
        float4 v = ((const float4*)(edge_fea + ((long)nidx[r] * 4 + j) * F_DIM))[colv];
        bf16x4 w = { (__bf16)v.x, (__bf16)v.y, (__bf16)v.z, (__bf16)v.w };
        *(bf16x4*)(&Aedge[j][r][0] + colv * 4) = w;
    }
    __syncthreads();

    const int lane = tid & 63;
    const int wave = tid >> 6;                 // 0..7 == head
    const int ml   = lane & 15;
    const int quad = lane >> 4;
    const int g0   = wave * 16;

    // ---- node GEMM: accN[mt] = feature_tile @ node_proj[t]^T (16 g-cols) ----
    floatx4 accN[2] = {};
    {
        const __bf16* a0 = &Afeat[ml][quad * 8];
        const __bf16* a1 = &Afeat[16 + ml][quad * 8];
        const __bf16* b0 = npb + t * (F_DIM * F_DIM) + (g0 + ml) * F_DIM + quad * 8;
        #pragma unroll
        for (int k0 = 0; k0 < 128; k0 += 32) {
            bf16x8 A0 = *(const bf16x8*)(a0 + k0);
            bf16x8 A1 = *(const bf16x8*)(a1 + k0);
            bf16x8 B0 = *(const bf16x8*)(b0 + k0);
            accN[0] = __builtin_amdgcn_mfma_f32_16x16x32_bf16(A0, B0, accN[0], 0, 0, 0);
            accN[1] = __builtin_amdgcn_mfma_f32_16x16x32_bf16(A1, B0, accN[1], 0, 0, 0);
        }
    }

    // ---- edge GEMMs + fused score reduction (DPP, VALU pipe) ----
    #pragma unroll
    for (int j = 0; j < 4; ++j) {
        floatx4 accE[2] = {};
        const __bf16* a0 = &Aedge[j][ml][quad * 8];
        const __bf16* a1 = &Aedge[j][16 + ml][quad * 8];
        const __bf16* b0 = epb + (t * 4 + j) * (F_DIM * F_DIM) + (g0 + ml) * F_DIM + quad * 8;
        #pragma unroll
        for (int k0 = 0; k0 < 128; k0 += 32) {
            bf16x8 A0 = *(const bf16x8*)(a0 + k0);
            bf16x8 A1 = *(const bf16x8*)(a1 + k0);
            bf16x8 B0 = *(const bf16x8*)(b0 + k0);
            accE[0] = __builtin_amdgcn_mfma_f32_16x16x32_bf16(A0, B0, accE[0], 0, 0, 0);
            accE[1] = __builtin_amdgcn_mfma_f32_16x16x32_bf16(A1, B0, accE[1], 0, 0, 0);
        }
        // score[m][h=wave][j] = (1/4) * sum_d node_p*edge_p ; d == lane&15
        #pragma unroll
        for (int mt = 0; mt < 2; ++mt) {
            floatx4 p = accN[mt] * accE[mt];
            p.x = sum16(p.x);
            p.y = sum16(p.y);
            p.z = sum16(p.z);
            p.w = sum16(p.w);
            if (ml == 0) {                       // one writer per 16-lane row
                int mb = mt * 16 + quad * 4;     // C/D row = quad*4+reg
                sc[mb + 0][j][wave] = p.x * 0.25f;
                sc[mb + 1][j][wave] = p.y * 0.25f;
                sc[mb + 2][j][wave] = p.z * 0.25f;
                sc[mb + 3][j][wave] = p.w * 0.25f;
            }
        }
    }
    __syncthreads();

    // ---- softmax over heads (axis=1 of [N,H,1,T]) -> out[n][j][h] ----
    if (tid < 128) {
        int node = tid >> 2, j = tid & 3;
        if (node < valid) {
            float v[8], m = -1e30f;
            #pragma unroll
            for (int h = 0; h < 8; ++h) { v[h] = sc[node][j][h]; m = fmaxf(m, v[h]); }
            float s = 0.f;
            #pragma unroll
            for (int h = 0; h < 8; ++h) { v[h] = __expf(v[h] - m); s += v[h]; }
            float r = 1.0f / s;
            float* o = out + (long)nidx[node] * (T_TYPES * H_HEADS) + j * H_HEADS;
            float4 o0 = { v[0] * r, v[1] * r, v[2] * r, v[3] * r };
            float4 o1 = { v[4] * r, v[5] * r, v[6] * r, v[7] * r };
            ((float4*)o)[0] = o0;
            ((float4*)o)[1] = o1;
        }
    }
}

extern "C" void kernel_launch(void* const* d_in, const int* in_sizes, int n_in,
                              void* d_out, int out_size, void* d_ws, size_t ws_size,
                              hipStream_t stream) {
    const float* feature   = (const float*)d_in[0];
    const float* edge_fea  = (const float*)d_in[1];
    const int*   mask      = (const int*)d_in[2];
    const float* node_proj = (const float*)d_in[3];
    const float* edge_proj = (const float*)d_in[4];
    float* out = (float*)d_out;

    char* ws = (char*)d_ws;
    int*    counts  = (int*)ws;
    int*    reorder = (int*)(ws + WS_REORDER);
    __bf16* npb     = (__bf16*)(ws + WS_NPB);
    __bf16* epb     = (__bf16*)(ws + WS_EPB);

    prep_kernel<<<320, 256, 0, stream>>>(node_proj, edge_proj, npb, epb, counts);
    bucket_kernel<<<(N_NODES + 255) / 256, 256, 0, stream>>>(mask, counts, reorder);
    int nblk = ((N_NODES + 31) / 32) * T_TYPES;   // flat grid, t = b & 3
    main_kernel<<<nblk, 512, 0, stream>>>(feature, edge_fea, counts, reorder, npb, epb, out);
}